// Round 3
// baseline (510.138 us; speedup 1.0000x reference)
//
#include <hip/hip_runtime.h>

#define BB 8
#define NN 2048
#define FF 64
#define HH 32
#define LK 512  // K-slice per wave; 4 waves cover K=2048

static __device__ __forceinline__ float warp_sum64(float v) {
  for (int off = 32; off; off >>= 1) v += __shfl_down(v, off, 64);
  return v;
}

static __device__ __forceinline__ unsigned int f2bf_rne(float f) {
  unsigned int u = __float_as_uint(f);
  return (u + 0x7fffu + ((u >> 16) & 1u)) >> 16;
}

#define B2F_LO(u) __uint_as_float((u) << 16)
#define B2F_HI(u) __uint_as_float((u) & 0xffff0000u)

// d_i = rowsum(a) + add_i ; dm = d^-1/2 ; add_i = (|a_ii| < 1e-7)
// Also converts A to bf16 (RNE) into Abf, fused with the mandatory read.
__global__ __launch_bounds__(256) void deg_cvt_kernel(const float* __restrict__ A,
                                                      float* __restrict__ dm,
                                                      float* __restrict__ addf,
                                                      unsigned short* __restrict__ Abf) {
  const int lane = threadIdx.x & 63;
  const int w = threadIdx.x >> 6;
  const size_t row = (size_t)blockIdx.x * 4 + w;  // flat b*N + n
  const size_t n = row & (NN - 1);
  const float* Ar = A + row * (size_t)NN;
  unsigned int* Abr = (unsigned int*)(Abf + row * (size_t)NN);  // 2 bf16 per uint
  float sum = 0.f;
#pragma unroll
  for (int it = 0; it < 8; ++it) {
    float4 v = *(const float4*)(Ar + it * 256 + lane * 4);
    sum += v.x + v.y + v.z + v.w;
    uint2 p;
    p.x = f2bf_rne(v.x) | (f2bf_rne(v.y) << 16);
    p.y = f2bf_rne(v.z) | (f2bf_rne(v.w) << 16);
    *(uint2*)(Abr + it * 128 + lane * 2) = p;
  }
  sum = warp_sum64(sum);
  if (lane == 0) {
    const float diag = Ar[n];
    const float ad = (fabsf(diag) < 1e-7f) ? 1.f : 0.f;
    dm[row] = 1.f / sqrtf(sum + ad);
    addf[row] = ad;
  }
}

// hs1[row][f] = dm_row * sum_c x[row][c] * W1[c][f]
__global__ __launch_bounds__(256) void xw_kernel(const float* __restrict__ x,
                                                 const float* __restrict__ W1,
                                                 const float* __restrict__ dm,
                                                 float* __restrict__ hs) {
  __shared__ float xs[8][FF + 1];
  __shared__ float wl[FF * HH];
  const int tid = threadIdx.x;
  const size_t row0 = (size_t)blockIdx.x * 8;
  for (int k = tid; k < FF * HH; k += 256) wl[k] = W1[k];
  for (int k = tid; k < 8 * FF; k += 256) xs[k >> 6][k & 63] = x[row0 * FF + k];
  __syncthreads();
  const int r = tid >> 5, c = tid & 31;
  float acc = 0.f;
#pragma unroll
  for (int k = 0; k < FF; ++k) acc = fmaf(xs[r][k], wl[k * HH + c], acc);
  const size_t row = row0 + r;
  hs[row * HH + c] = dm[row] * acc;
}

// One fused GCN layer: block = 4 waves = 64 rows, full K in-block.
// Wave w handles K-slice [w*512, w*512+512); lane <-> row; hs reads are
// wave-uniform (scalar path). Cross-wave LDS reduce, then in-block epilogue:
// h = relu(dm*(sum + add*hs_in) + bias), then either hs_next = dm*(h @ Wn)
// or block-local max + one atomicMax per (b,f) per block.
__global__ __launch_bounds__(256) void layer_kernel(const unsigned short* __restrict__ Abf,
                                                    const float* __restrict__ hs_in,
                                                    const float* __restrict__ dm,
                                                    const float* __restrict__ addf,
                                                    const float* __restrict__ bias,
                                                    const float* __restrict__ Wn,
                                                    float* __restrict__ hs_next,
                                                    unsigned int* __restrict__ gmax,
                                                    const int do_pool) {
  __shared__ float red[4 * 64 * 33];   // 33.8 KB
  __shared__ float hbuf[64 * 33];      // 8.4 KB
  __shared__ float wl[HH * HH];        // 4 KB
  __shared__ float pbuf[8 * HH];       // 1 KB

  const int tid = threadIdx.x;
  const int rb = blockIdx.x & 31;
  const int b = blockIdx.x >> 5;
  const int lane = tid & 63;
  const int w = __builtin_amdgcn_readfirstlane(tid >> 6);

  if (!do_pool)
    for (int k = tid; k < HH * HH; k += 256) wl[k] = Wn[k];

  const int row = rb * 64 + lane;
  const int j0 = w * LK;
  const uint4* __restrict__ Ap =
      (const uint4*)(Abf + ((size_t)b * NN + row) * NN + j0);
  const float* __restrict__ hsb = hs_in + ((size_t)b * NN + j0) * HH;

  float acc[HH];
#pragma unroll
  for (int f = 0; f < HH; ++f) acc[f] = 0.f;

  uint4 cur = Ap[0];
#pragma unroll 4
  for (int c = 0; c < LK / 8 - 1; ++c) {
    const uint4 nxt = Ap[c + 1];  // prefetch next 16 B while computing
    const float* __restrict__ hr = hsb + (size_t)c * 8 * HH;
    float av[8];
    av[0] = B2F_LO(cur.x); av[1] = B2F_HI(cur.x);
    av[2] = B2F_LO(cur.y); av[3] = B2F_HI(cur.y);
    av[4] = B2F_LO(cur.z); av[5] = B2F_HI(cur.z);
    av[6] = B2F_LO(cur.w); av[7] = B2F_HI(cur.w);
#pragma unroll
    for (int jj = 0; jj < 8; ++jj)
#pragma unroll
      for (int f = 0; f < HH; ++f)
        acc[f] = fmaf(av[jj], hr[jj * HH + f], acc[f]);
    cur = nxt;
  }
  {  // peeled last iteration
    const int c = LK / 8 - 1;
    const float* __restrict__ hr = hsb + (size_t)c * 8 * HH;
    float av[8];
    av[0] = B2F_LO(cur.x); av[1] = B2F_HI(cur.x);
    av[2] = B2F_LO(cur.y); av[3] = B2F_HI(cur.y);
    av[4] = B2F_LO(cur.z); av[5] = B2F_HI(cur.z);
    av[6] = B2F_LO(cur.w); av[7] = B2F_HI(cur.w);
#pragma unroll
    for (int jj = 0; jj < 8; ++jj)
#pragma unroll
      for (int f = 0; f < HH; ++f)
        acc[f] = fmaf(av[jj], hr[jj * HH + f], acc[f]);
  }

  float* my = &red[(w * 64 + lane) * 33];
#pragma unroll
  for (int f = 0; f < HH; ++f) my[f] = acc[f];
  __syncthreads();

  const int f = tid & 31;
  const int l0 = tid >> 5;
  float hv[8];
#pragma unroll
  for (int l8 = 0; l8 < 8; ++l8) {
    const int l = l0 + l8 * 8;
    const float psum = red[l * 33 + f] + red[(64 + l) * 33 + f] +
                       red[(128 + l) * 33 + f] + red[(192 + l) * 33 + f];
    const int rg = b * NN + rb * 64 + l;
    float h = fmaf(dm[rg], psum + addf[rg] * hs_in[(size_t)rg * HH + f], bias[f]);
    hv[l8] = fmaxf(h, 0.f);
  }

  if (do_pool) {
    float pm = hv[0];
#pragma unroll
    for (int l8 = 1; l8 < 8; ++l8) pm = fmaxf(pm, hv[l8]);
    pbuf[l0 * HH + f] = pm;
    __syncthreads();
    if (tid < HH) {
      float m = pbuf[tid];
#pragma unroll
      for (int r = 1; r < 8; ++r) m = fmaxf(m, pbuf[r * HH + tid]);
      atomicMax(&gmax[b * HH + tid], __float_as_uint(m));
    }
  } else {
#pragma unroll
    for (int l8 = 0; l8 < 8; ++l8) hbuf[(l0 + l8 * 8) * 33 + f] = hv[l8];
    __syncthreads();
#pragma unroll
    for (int l8 = 0; l8 < 8; ++l8) {
      const int l = l0 + l8 * 8;
      const int rg = b * NN + rb * 64 + l;
      float acc2 = 0.f;
#pragma unroll
      for (int k = 0; k < HH; ++k)
        acc2 = fmaf(hbuf[l * 33 + k], wl[k * HH + f], acc2);
      hs_next[(size_t)rg * HH + f] = dm[rg] * acc2;
    }
  }
}

// out[b] = (relu(g @ Wf1 + bf1)) @ Wf2 + bf2 ; one wave per batch
__global__ __launch_bounds__(64) void head_kernel(const unsigned int* __restrict__ gmax,
                                                  const float* __restrict__ Wf1,
                                                  const float* __restrict__ bf1,
                                                  const float* __restrict__ Wf2,
                                                  const float* __restrict__ bf2,
                                                  float* __restrict__ out) {
  const int b = blockIdx.x;
  const int t = threadIdx.x;  // 0..63 hidden units
  float acc = bf1[t];
#pragma unroll
  for (int c = 0; c < HH; ++c)
    acc = fmaf(__uint_as_float(gmax[b * HH + c]), Wf1[c * (2 * HH) + t], acc);
  acc = fmaxf(acc, 0.f);
  float v = acc * Wf2[t];
  v = warp_sum64(v);
  if (t == 0) out[b] = v + bf2[0];
}

extern "C" void kernel_launch(void* const* d_in, const int* in_sizes, int n_in,
                              void* d_out, int out_size, void* d_ws, size_t ws_size,
                              hipStream_t stream) {
  const float* x   = (const float*)d_in[0];
  const float* a   = (const float*)d_in[1];
  const float* W1  = (const float*)d_in[2];
  const float* b1  = (const float*)d_in[3];
  const float* W2  = (const float*)d_in[4];
  const float* b2  = (const float*)d_in[5];
  const float* W3  = (const float*)d_in[6];
  const float* b3  = (const float*)d_in[7];
  const float* Wf1 = (const float*)d_in[8];
  const float* bf1 = (const float*)d_in[9];
  const float* Wf2 = (const float*)d_in[10];
  const float* bf2 = (const float*)d_in[11];
  float* out = (float*)d_out;

  float* ws = (float*)d_ws;
  const size_t BN = (size_t)BB * NN;  // 16384
  float* dm   = ws;                    // 16384
  float* addf = dm + BN;               // 16384
  float* hs_a = addf + BN;             // BN*32 (2 MB)
  float* hs_b = hs_a + BN * HH;        // BN*32 (2 MB)
  unsigned int* gmax = (unsigned int*)(hs_b + BN * HH);
  unsigned short* Abf = (unsigned short*)(gmax + BB * HH);  // 67 MB bf16 A
  // total ws use ~71.3 MB

  hipMemsetAsync(gmax, 0, BB * HH * sizeof(unsigned int), stream);

  deg_cvt_kernel<<<BN / 4, 256, 0, stream>>>(a, dm, addf, Abf);
  xw_kernel<<<BN / 8, 256, 0, stream>>>(x, W1, dm, hs_a);

  layer_kernel<<<BB * 32, 256, 0, stream>>>(Abf, hs_a, dm, addf, b1, W2, hs_b, nullptr, 0);
  layer_kernel<<<BB * 32, 256, 0, stream>>>(Abf, hs_b, dm, addf, b2, W3, hs_a, nullptr, 0);
  layer_kernel<<<BB * 32, 256, 0, stream>>>(Abf, hs_a, dm, addf, b3, nullptr, nullptr, gmax, 1);

  head_kernel<<<BB, 64, 0, stream>>>(gmax, Wf1, bf1, Wf2, bf2, out);
}

// Round 4
// 291.023 us; speedup vs baseline: 1.7529x; 1.7529x over previous
//
#include <hip/hip_runtime.h>

#define BB 8
#define NN 2048
#define FF 64
#define HH 32

typedef __attribute__((ext_vector_type(8))) short short8;
typedef __attribute__((ext_vector_type(4))) float floatx4;

static __device__ __forceinline__ float warp_sum64(float v) {
  for (int off = 32; off; off >>= 1) v += __shfl_down(v, off, 64);
  return v;
}

static __device__ __forceinline__ unsigned int f2bf_rne(float f) {
  unsigned int u = __float_as_uint(f);
  return (u + 0x7fffu + ((u >> 16) & 1u)) >> 16;
}
static __device__ __forceinline__ float bf2f(unsigned short s) {
  return __uint_as_float(((unsigned int)s) << 16);
}

#define GLOAD_LDS16(g, l)                                                 \
  __builtin_amdgcn_global_load_lds(                                       \
      (const __attribute__((address_space(1))) unsigned int*)(g),         \
      (__attribute__((address_space(3))) unsigned int*)(l), 16, 0, 0)

// d_i = rowsum(a) + add_i ; dm = d^-1/2 ; add_i = (|a_ii| < 1e-7)
// Also converts A to bf16 (RNE) into Abf, fused with the mandatory read.
__global__ __launch_bounds__(256) void deg_cvt_kernel(const float* __restrict__ A,
                                                      float* __restrict__ dm,
                                                      float* __restrict__ addf,
                                                      unsigned short* __restrict__ Abf) {
  const int lane = threadIdx.x & 63;
  const int w = threadIdx.x >> 6;
  const size_t row = (size_t)blockIdx.x * 4 + w;  // flat b*N + n
  const size_t n = row & (NN - 1);
  const float* Ar = A + row * (size_t)NN;
  unsigned int* Abr = (unsigned int*)(Abf + row * (size_t)NN);
  float sum = 0.f;
#pragma unroll
  for (int it = 0; it < 8; ++it) {
    float4 v = *(const float4*)(Ar + it * 256 + lane * 4);
    sum += v.x + v.y + v.z + v.w;
    uint2 p;
    p.x = f2bf_rne(v.x) | (f2bf_rne(v.y) << 16);
    p.y = f2bf_rne(v.z) | (f2bf_rne(v.w) << 16);
    *(uint2*)(Abr + it * 128 + lane * 2) = p;
  }
  sum = warp_sum64(sum);
  if (lane == 0) {
    const float diag = Ar[n];
    const float ad = (fabsf(diag) < 1e-7f) ? 1.f : 0.f;
    dm[row] = 1.f / sqrtf(sum + ad);
    addf[row] = ad;
  }
}

// hst1[b][f][n] = bf16( dm_row * sum_c x[row][c] * W1[c][f] ), row = b*N+n
__global__ __launch_bounds__(256) void xw_kernel(const float* __restrict__ x,
                                                 const float* __restrict__ W1,
                                                 const float* __restrict__ dm,
                                                 unsigned short* __restrict__ hst) {
  __shared__ float xs[8][FF + 1];
  __shared__ float wl[FF * HH];
  const int tid = threadIdx.x;
  const size_t row0 = (size_t)blockIdx.x * 8;
  for (int k = tid; k < FF * HH; k += 256) wl[k] = W1[k];
  for (int k = tid; k < 8 * FF; k += 256) xs[k >> 6][k & 63] = x[row0 * FF + k];
  __syncthreads();
  const int r = tid >> 5, c = tid & 31;
  float acc = 0.f;
#pragma unroll
  for (int k = 0; k < FF; ++k) acc = fmaf(xs[r][k], wl[k * HH + c], acc);
  const size_t row = row0 + r;
  const int b = (int)(row >> 11);
  const int n = (int)(row & (NN - 1));
  hst[((size_t)b * HH + c) * NN + n] = (unsigned short)f2bf_rne(dm[row] * acc);
}

// One fused GCN layer via MFMA.
// Block: 4 waves, 32-row M-tile, N=32, K=2048 in 16 chunks of 128.
// Wave w owns (mt=w>>1, nt=w&1): one 16x16 C tile over full K (no reduce).
// A (bf16, row-major) and hst (bf16, [f][k]) staged via global_load_lds with
// XOR-granule swizzle (16B granule g stored at (g&8)|((g&7)^(row&7))) so
// ds_read_b128 fragment reads are 2-way-conflict (free) while DMA stays
// contiguous. Double-buffered; barrier-drain overlap across 2 blocks/CU.
__global__ __launch_bounds__(256) void layer_kernel(const unsigned short* __restrict__ Abf,
                                                    const unsigned short* __restrict__ hst_in,
                                                    const float* __restrict__ dm,
                                                    const float* __restrict__ addf,
                                                    const float* __restrict__ bias,
                                                    const float* __restrict__ Wn,
                                                    unsigned short* __restrict__ hst_next,
                                                    unsigned int* __restrict__ gmax,
                                                    const int do_pool) {
  __shared__ unsigned char Asm[2][8192];   // [32 rows][16 granules x 16B]
  __shared__ unsigned char Bsm[2][8192];   // [32 f-rows][16 granules x 16B]
  __shared__ float wl[HH * HH];
  __shared__ float hbuf[32][HH + 1];
  __shared__ float pbuf[8][HH];

  const int tid = threadIdx.x;
  const int mb = blockIdx.x & 63;
  const int b = blockIdx.x >> 6;
  const int mrow0 = mb * 32;
  const int lane = tid & 63;
  const int w = tid >> 6;
  const int mt = w >> 1, nt = w & 1;

  if (!do_pool)
    for (int k = tid; k < HH * HH; k += 256) wl[k] = Wn[k];

  // --- DMA staging slot (per thread, constant across chunks) ---
  const int r0 = tid >> 4;        // 0..15 (row within issue)
  const int gd = tid & 15;        // dest granule
  const int gs = (gd & 8) | ((gd & 7) ^ (r0 & 7));  // source granule
  const unsigned short* aSrc0 =
      Abf + ((size_t)(b * NN + mrow0 + r0) * NN) + gs * 8;
  const unsigned short* bSrc0 =
      hst_in + ((size_t)(b * HH + r0) * NN) + gs * 8;
  const int waveBase = (tid >> 6) * 1024;  // wave-uniform LDS base offset

  // --- fragment LDS byte offsets (constant across chunks) ---
  const int q = lane >> 4;
  const int arow = mt * 16 + (lane & 15);
  const int nrow = nt * 16 + (lane & 15);
  int aoff[4], boff[4];
#pragma unroll
  for (int ks = 0; ks < 4; ++ks) {
    const int g = ks * 4 + q;
    aoff[ks] = arow * 256 + (((g & 8) | ((g & 7) ^ (arow & 7))) * 16);
    boff[ks] = nrow * 256 + (((g & 8) | ((g & 7) ^ (nrow & 7))) * 16);
  }

  floatx4 acc = {0.f, 0.f, 0.f, 0.f};

#define STAGE(k0, p)                                                     \
  do {                                                                   \
    GLOAD_LDS16(aSrc0 + (k0), &Asm[p][waveBase]);                        \
    GLOAD_LDS16(aSrc0 + (k0) + 16 * (size_t)NN, &Asm[p][4096 + waveBase]); \
    GLOAD_LDS16(bSrc0 + (k0), &Bsm[p][waveBase]);                        \
    GLOAD_LDS16(bSrc0 + (k0) + 16 * (size_t)NN, &Bsm[p][4096 + waveBase]); \
  } while (0)

  STAGE(0, 0);
#pragma unroll 4
  for (int c = 0; c < 16; ++c) {
    __syncthreads();  // drains DMA for chunk c; protects buffer reuse
    if (c + 1 < 16) STAGE((c + 1) * 128, (c + 1) & 1);
    const unsigned char* Ab = Asm[c & 1];
    const unsigned char* Bb = Bsm[c & 1];
#pragma unroll
    for (int ks = 0; ks < 4; ++ks) {
      short8 af = *(const short8*)(Ab + aoff[ks]);
      short8 bf = *(const short8*)(Bb + boff[ks]);
      acc = __builtin_amdgcn_mfma_f32_16x16x32_bf16(af, bf, acc, 0, 0, 0);
    }
  }

  // --- epilogue: h = relu(dm*(acc + add*hs_in) + bias) ---
  const int colc = nt * 16 + (lane & 15);
  __syncthreads();
#pragma unroll
  for (int r = 0; r < 4; ++r) {
    const int rowb = mt * 16 + q * 4 + r;
    const int rg = b * NN + mrow0 + rowb;
    const float hsin = bf2f(hst_in[((size_t)b * HH + colc) * NN + mrow0 + rowb]);
    const float h = fmaf(dm[rg], acc[r] + addf[rg] * hsin, bias[colc]);
    hbuf[rowb][colc] = fmaxf(h, 0.f);
  }
  __syncthreads();

  const int col = tid & 31;
  const int rq = tid >> 5;  // 0..7 -> rows rq*4 .. rq*4+3
  if (do_pool) {
    float m = hbuf[rq * 4][col];
#pragma unroll
    for (int i = 1; i < 4; ++i) m = fmaxf(m, hbuf[rq * 4 + i][col]);
    pbuf[rq][col] = m;
    __syncthreads();
    if (tid < HH) {
      float mm = pbuf[0][tid];
#pragma unroll
      for (int r = 1; r < 8; ++r) mm = fmaxf(mm, pbuf[r][tid]);
      atomicMax(&gmax[b * HH + tid], __float_as_uint(mm));
    }
  } else {
    unsigned short outv[4];
#pragma unroll
    for (int i = 0; i < 4; ++i) {
      const int row = rq * 4 + i;
      const int rg = b * NN + mrow0 + row;
      float acc2 = 0.f;
#pragma unroll
      for (int k = 0; k < HH; ++k)
        acc2 = fmaf(hbuf[row][k], wl[k * HH + col], acc2);
      outv[i] = (unsigned short)f2bf_rne(dm[rg] * acc2);
    }
    *(ushort4*)(hst_next + ((size_t)b * HH + col) * NN + mrow0 + rq * 4) =
        *(ushort4*)outv;
  }
#undef STAGE
}

// out[b] = (relu(g @ Wf1 + bf1)) @ Wf2 + bf2 ; one wave per batch
__global__ __launch_bounds__(64) void head_kernel(const unsigned int* __restrict__ gmax,
                                                  const float* __restrict__ Wf1,
                                                  const float* __restrict__ bf1,
                                                  const float* __restrict__ Wf2,
                                                  const float* __restrict__ bf2,
                                                  float* __restrict__ out) {
  const int b = blockIdx.x;
  const int t = threadIdx.x;  // 0..63 hidden units
  float acc = bf1[t];
#pragma unroll
  for (int c = 0; c < HH; ++c)
    acc = fmaf(__uint_as_float(gmax[b * HH + c]), Wf1[c * (2 * HH) + t], acc);
  acc = fmaxf(acc, 0.f);
  float v = acc * Wf2[t];
  v = warp_sum64(v);
  if (t == 0) out[b] = v + bf2[0];
}

extern "C" void kernel_launch(void* const* d_in, const int* in_sizes, int n_in,
                              void* d_out, int out_size, void* d_ws, size_t ws_size,
                              hipStream_t stream) {
  const float* x   = (const float*)d_in[0];
  const float* a   = (const float*)d_in[1];
  const float* W1  = (const float*)d_in[2];
  const float* b1  = (const float*)d_in[3];
  const float* W2  = (const float*)d_in[4];
  const float* b2  = (const float*)d_in[5];
  const float* W3  = (const float*)d_in[6];
  const float* b3  = (const float*)d_in[7];
  const float* Wf1 = (const float*)d_in[8];
  const float* bf1 = (const float*)d_in[9];
  const float* Wf2 = (const float*)d_in[10];
  const float* bf2 = (const float*)d_in[11];
  float* out = (float*)d_out;

  float* ws = (float*)d_ws;
  const size_t BN = (size_t)BB * NN;  // 16384
  float* dm   = ws;                                     // 16384 f
  float* addf = dm + BN;                                // 16384 f
  unsigned int* gmax = (unsigned int*)(addf + BN);      // 256 u32
  unsigned short* hst_a = (unsigned short*)(gmax + 256);  // BN*32 u16 (1 MB)
  unsigned short* hst_b = hst_a + BN * HH;              // 1 MB
  unsigned short* Abf = hst_b + BN * HH;                // 67 MB bf16 A
  // total ws use ~69.5 MB

  hipMemsetAsync(gmax, 0, BB * HH * sizeof(unsigned int), stream);

  deg_cvt_kernel<<<BN / 4, 256, 0, stream>>>(a, dm, addf, Abf);
  xw_kernel<<<BN / 8, 256, 0, stream>>>(x, W1, dm, hst_a);

  layer_kernel<<<BB * 64, 256, 0, stream>>>(Abf, hst_a, dm, addf, b1, W2, hst_b, nullptr, 0);
  layer_kernel<<<BB * 64, 256, 0, stream>>>(Abf, hst_b, dm, addf, b2, W3, hst_a, nullptr, 0);
  layer_kernel<<<BB * 64, 256, 0, stream>>>(Abf, hst_a, dm, addf, b3, nullptr, nullptr, gmax, 1);

  head_kernel<<<BB, 64, 0, stream>>>(gmax, Wf1, bf1, Wf2, bf2, out);
}

// Round 5
// 279.526 us; speedup vs baseline: 1.8250x; 1.0411x over previous
//
#include <hip/hip_runtime.h>

#define BB 8
#define NN 2048
#define FF 64
#define HH 32
#define CK 256           // K-chunk
#define NCH (NN / CK)    // 8 chunks

typedef __attribute__((ext_vector_type(8))) short short8;
typedef __attribute__((ext_vector_type(4))) float floatx4;

static __device__ __forceinline__ float warp_sum64(float v) {
  for (int off = 32; off; off >>= 1) v += __shfl_down(v, off, 64);
  return v;
}

static __device__ __forceinline__ unsigned int f2bf_rne(float f) {
  unsigned int u = __float_as_uint(f);
  return (u + 0x7fffu + ((u >> 16) & 1u)) >> 16;
}
static __device__ __forceinline__ float bf2f(unsigned short s) {
  return __uint_as_float(((unsigned int)s) << 16);
}

#define GLOAD_LDS16(g, l)                                                 \
  __builtin_amdgcn_global_load_lds(                                       \
      (const __attribute__((address_space(1))) unsigned int*)(g),         \
      (__attribute__((address_space(3))) unsigned int*)(l), 16, 0, 0)

// d_i = rowsum(a) + add_i ; dm = d^-1/2 ; add_i = (|a_ii| < 1e-7)
// Also converts A to bf16 (RNE) into Abf, fused with the mandatory read.
__global__ __launch_bounds__(256) void deg_cvt_kernel(const float* __restrict__ A,
                                                      float* __restrict__ dm,
                                                      float* __restrict__ addf,
                                                      unsigned short* __restrict__ Abf) {
  const int lane = threadIdx.x & 63;
  const int w = threadIdx.x >> 6;
  const size_t row = (size_t)blockIdx.x * 4 + w;  // flat b*N + n
  const size_t n = row & (NN - 1);
  const float* Ar = A + row * (size_t)NN;
  unsigned int* Abr = (unsigned int*)(Abf + row * (size_t)NN);
  float sum = 0.f;
#pragma unroll
  for (int it = 0; it < 8; ++it) {
    float4 v = *(const float4*)(Ar + it * 256 + lane * 4);
    sum += v.x + v.y + v.z + v.w;
    uint2 p;
    p.x = f2bf_rne(v.x) | (f2bf_rne(v.y) << 16);
    p.y = f2bf_rne(v.z) | (f2bf_rne(v.w) << 16);
    *(uint2*)(Abr + it * 128 + lane * 2) = p;
  }
  sum = warp_sum64(sum);
  if (lane == 0) {
    const float diag = Ar[n];
    const float ad = (fabsf(diag) < 1e-7f) ? 1.f : 0.f;
    dm[row] = 1.f / sqrtf(sum + ad);
    addf[row] = ad;
  }
}

// hst1[b][f][n] = bf16( dm_row * sum_c x[row][c] * W1[c][f] ), row = b*N+n
__global__ __launch_bounds__(256) void xw_kernel(const float* __restrict__ x,
                                                 const float* __restrict__ W1,
                                                 const float* __restrict__ dm,
                                                 unsigned short* __restrict__ hst) {
  __shared__ float xs[8][FF + 1];
  __shared__ float wl[FF * HH];
  const int tid = threadIdx.x;
  const size_t row0 = (size_t)blockIdx.x * 8;
  for (int k = tid; k < FF * HH; k += 256) wl[k] = W1[k];
  for (int k = tid; k < 8 * FF; k += 256) xs[k >> 6][k & 63] = x[row0 * FF + k];
  __syncthreads();
  const int r = tid >> 5, c = tid & 31;
  float acc = 0.f;
#pragma unroll
  for (int k = 0; k < FF; ++k) acc = fmaf(xs[r][k], wl[k * HH + c], acc);
  const size_t row = row0 + r;
  const int b = (int)(row >> 11);
  const int n = (int)(row & (NN - 1));
  hst[((size_t)b * HH + c) * NN + n] = (unsigned short)f2bf_rne(dm[row] * acc);
}

// One fused GCN layer via MFMA.
// Block: 4 waves, 32-row M-tile, N=32, K=2048 in 8 chunks of 256.
// Wave w owns (mt=w>>1, nt=w&1): one 16x16 C tile over full K (no reduce).
// A (bf16, row-major) and hst (bf16, [f][k]) staged via global_load_lds,
// double-buffered (8 barrier drains total), XOR-granule swizzle keeps
// ds_read_b128 at 2-way conflicts (free) with a contiguous DMA lane map.
// Buffer layout: 32 rows x 512 B (32 granules of 16 B, swizzled by row&7).
__global__ __launch_bounds__(256) void layer_kernel(const unsigned short* __restrict__ Abf,
                                                    const unsigned short* __restrict__ hst_in,
                                                    const float* __restrict__ dm,
                                                    const float* __restrict__ addf,
                                                    const float* __restrict__ bias,
                                                    const float* __restrict__ Wn,
                                                    unsigned short* __restrict__ hst_next,
                                                    unsigned int* __restrict__ gmax,
                                                    const int do_pool) {
  __shared__ unsigned char Asm[2][16384];  // [32 rows][32 granules x 16B]
  __shared__ unsigned char Bsm[2][16384];
  __shared__ float wl[HH * HH];
  __shared__ float hbuf[32][HH + 1];
  __shared__ float pbuf[8][HH];

  const int tid = threadIdx.x;
  const int mb = blockIdx.x & 63;
  const int b = blockIdx.x >> 6;
  const int mrow0 = mb * 32;
  const int lane = tid & 63;
  const int w = tid >> 6;
  const int mt = w >> 1, nt = w & 1;

  if (!do_pool)
    for (int k = tid; k < HH * HH; k += 256) wl[k] = Wn[k];

  // --- DMA staging map (per thread, constant across chunks) ---
  // Issue i (i=0..3): dest row r = i*8 + (tid>>5), dest granule gd = tid&31.
  // Source granule gs has (gs&7) = (gd&7) ^ (r&7); r&7 == tid>>5 (0..7).
  const int t5 = tid >> 5;
  const int gd = tid & 31;
  const int gs = (gd & 24) | ((gd & 7) ^ t5);
  const unsigned short* aSrcT =
      Abf + ((size_t)(b * NN + mrow0 + t5) * NN) + gs * 8;
  const unsigned short* bSrcT =
      hst_in + ((size_t)(b * HH + t5) * NN) + gs * 8;
  const int waveBase = w * 1024;  // wave-uniform part of dest offset

  // --- fragment LDS byte offsets (constant across chunks) ---
  const int q = lane >> 4;
  const int arow = mt * 16 + (lane & 15);
  const int nrow = nt * 16 + (lane & 15);
  int aoff[NCH], boff[NCH];
#pragma unroll
  for (int ks = 0; ks < NCH; ++ks) {
    const int g = ks * 4 + q;
    aoff[ks] = arow * 512 + (((g & 24) | ((g & 7) ^ (arow & 7))) * 16);
    boff[ks] = nrow * 512 + (((g & 24) | ((g & 7) ^ (nrow & 7))) * 16);
  }

  floatx4 acc = {0.f, 0.f, 0.f, 0.f};

#define STAGE(k0, p)                                                       \
  do {                                                                     \
    _Pragma("unroll")                                                      \
    for (int i = 0; i < 4; ++i) {                                          \
      GLOAD_LDS16(aSrcT + (k0) + i * 8 * (size_t)NN,                       \
                  &Asm[p][i * 4096 + waveBase]);                           \
      GLOAD_LDS16(bSrcT + (k0) + i * 8 * (size_t)NN,                       \
                  &Bsm[p][i * 4096 + waveBase]);                           \
    }                                                                      \
  } while (0)

  STAGE(0, 0);
#pragma unroll
  for (int c = 0; c < NCH; ++c) {
    __syncthreads();  // drains DMA for chunk c; protects buffer reuse
    if (c + 1 < NCH) STAGE((c + 1) * CK, (c + 1) & 1);
    const unsigned char* Ab = Asm[c & 1];
    const unsigned char* Bb = Bsm[c & 1];
#pragma unroll
    for (int ks = 0; ks < 8; ++ks) {
      short8 af = *(const short8*)(Ab + aoff[ks]);
      short8 bf = *(const short8*)(Bb + boff[ks]);
      acc = __builtin_amdgcn_mfma_f32_16x16x32_bf16(af, bf, acc, 0, 0, 0);
    }
  }

  // --- epilogue: h = relu(dm*(acc + add*hs_in) + bias) ---
  const int colc = nt * 16 + (lane & 15);
  __syncthreads();
#pragma unroll
  for (int r = 0; r < 4; ++r) {
    const int rowb = mt * 16 + q * 4 + r;
    const int rg = b * NN + mrow0 + rowb;
    const float hsin = bf2f(hst_in[((size_t)b * HH + colc) * NN + mrow0 + rowb]);
    const float h = fmaf(dm[rg], acc[r] + addf[rg] * hsin, bias[colc]);
    hbuf[rowb][colc] = fmaxf(h, 0.f);
  }
  __syncthreads();

  const int col = tid & 31;
  const int rq = tid >> 5;  // 0..7 -> rows rq*4 .. rq*4+3
  if (do_pool) {
    float m = hbuf[rq * 4][col];
#pragma unroll
    for (int i = 1; i < 4; ++i) m = fmaxf(m, hbuf[rq * 4 + i][col]);
    pbuf[rq][col] = m;
    __syncthreads();
    if (tid < HH) {
      float mm = pbuf[0][tid];
#pragma unroll
      for (int r = 1; r < 8; ++r) mm = fmaxf(mm, pbuf[r][tid]);
      atomicMax(&gmax[b * HH + tid], __float_as_uint(mm));
    }
  } else {
    unsigned short outv[4];
#pragma unroll
    for (int i = 0; i < 4; ++i) {
      const int row = rq * 4 + i;
      const int rg = b * NN + mrow0 + row;
      float acc2 = 0.f;
#pragma unroll
      for (int k = 0; k < HH; ++k)
        acc2 = fmaf(hbuf[row][k], wl[k * HH + col], acc2);
      outv[i] = (unsigned short)f2bf_rne(dm[rg] * acc2);
    }
    *(ushort4*)(hst_next + ((size_t)b * HH + col) * NN + mrow0 + rq * 4) =
        *(ushort4*)outv;
  }
#undef STAGE
}

// out[b] = (relu(g @ Wf1 + bf1)) @ Wf2 + bf2 ; one wave per batch
__global__ __launch_bounds__(64) void head_kernel(const unsigned int* __restrict__ gmax,
                                                  const float* __restrict__ Wf1,
                                                  const float* __restrict__ bf1,
                                                  const float* __restrict__ Wf2,
                                                  const float* __restrict__ bf2,
                                                  float* __restrict__ out) {
  const int b = blockIdx.x;
  const int t = threadIdx.x;  // 0..63 hidden units
  float acc = bf1[t];
#pragma unroll
  for (int c = 0; c < HH; ++c)
    acc = fmaf(__uint_as_float(gmax[b * HH + c]), Wf1[c * (2 * HH) + t], acc);
  acc = fmaxf(acc, 0.f);
  float v = acc * Wf2[t];
  v = warp_sum64(v);
  if (t == 0) out[b] = v + bf2[0];
}

extern "C" void kernel_launch(void* const* d_in, const int* in_sizes, int n_in,
                              void* d_out, int out_size, void* d_ws, size_t ws_size,
                              hipStream_t stream) {
  const float* x   = (const float*)d_in[0];
  const float* a   = (const float*)d_in[1];
  const float* W1  = (const float*)d_in[2];
  const float* b1  = (const float*)d_in[3];
  const float* W2  = (const float*)d_in[4];
  const float* b2  = (const float*)d_in[5];
  const float* W3  = (const float*)d_in[6];
  const float* b3  = (const float*)d_in[7];
  const float* Wf1 = (const float*)d_in[8];
  const float* bf1 = (const float*)d_in[9];
  const float* Wf2 = (const float*)d_in[10];
  const float* bf2 = (const float*)d_in[11];
  float* out = (float*)d_out;

  float* ws = (float*)d_ws;
  const size_t BN = (size_t)BB * NN;  // 16384
  float* dm   = ws;                                     // 16384 f
  float* addf = dm + BN;                                // 16384 f
  unsigned int* gmax = (unsigned int*)(addf + BN);      // 256 u32
  unsigned short* hst_a = (unsigned short*)(gmax + 256);  // BN*32 u16 (1 MB)
  unsigned short* hst_b = hst_a + BN * HH;              // 1 MB
  unsigned short* Abf = hst_b + BN * HH;                // 67 MB bf16 A
  // total ws use ~69.5 MB

  hipMemsetAsync(gmax, 0, BB * HH * sizeof(unsigned int), stream);

  deg_cvt_kernel<<<BN / 4, 256, 0, stream>>>(a, dm, addf, Abf);
  xw_kernel<<<BN / 8, 256, 0, stream>>>(x, W1, dm, hst_a);

  layer_kernel<<<BB * 64, 256, 0, stream>>>(Abf, hst_a, dm, addf, b1, W2, hst_b, nullptr, 0);
  layer_kernel<<<BB * 64, 256, 0, stream>>>(Abf, hst_b, dm, addf, b2, W3, hst_a, nullptr, 0);
  layer_kernel<<<BB * 64, 256, 0, stream>>>(Abf, hst_a, dm, addf, b3, nullptr, nullptr, gmax, 1);

  head_kernel<<<BB, 64, 0, stream>>>(gmax, Wf1, bf1, Wf2, bf2, out);
}

// Round 7
// 278.063 us; speedup vs baseline: 1.8346x; 1.0053x over previous
//
#include <hip/hip_runtime.h>

#define BB 8
#define NN 2048
#define FF 64
#define HH 32
#define CK 128          // K per chunk
#define NCHK (NN / CK)  // 16 chunks

typedef __attribute__((ext_vector_type(8))) short short8;
typedef __attribute__((ext_vector_type(4))) float floatx4;

static __device__ __forceinline__ float warp_sum64(float v) {
  for (int off = 32; off; off >>= 1) v += __shfl_down(v, off, 64);
  return v;
}

static __device__ __forceinline__ unsigned int f2bf_rne(float f) {
  unsigned int u = __float_as_uint(f);
  return (u + 0x7fffu + ((u >> 16) & 1u)) >> 16;
}
static __device__ __forceinline__ float bf2f(unsigned short s) {
  return __uint_as_float(((unsigned int)s) << 16);
}

#define GLOAD_LDS16(g, l)                                                 \
  __builtin_amdgcn_global_load_lds(                                       \
      (const __attribute__((address_space(1))) unsigned int*)(g),         \
      (__attribute__((address_space(3))) unsigned int*)(l), 16, 0, 0)

// d_i = rowsum(a) + add_i ; dm = d^-1/2 ; add_i = (|a_ii| < 1e-7)
// Also converts A to bf16 (RNE) into Abf, fused with the mandatory read.
__global__ __launch_bounds__(256) void deg_cvt_kernel(const float* __restrict__ A,
                                                      float* __restrict__ dm,
                                                      float* __restrict__ addf,
                                                      unsigned short* __restrict__ Abf) {
  const int lane = threadIdx.x & 63;
  const int w = threadIdx.x >> 6;
  const size_t row = (size_t)blockIdx.x * 4 + w;  // flat b*N + n
  const size_t n = row & (NN - 1);
  const float* Ar = A + row * (size_t)NN;
  unsigned int* Abr = (unsigned int*)(Abf + row * (size_t)NN);
  float sum = 0.f;
#pragma unroll
  for (int it = 0; it < 8; ++it) {
    float4 v = *(const float4*)(Ar + it * 256 + lane * 4);
    sum += v.x + v.y + v.z + v.w;
    uint2 p;
    p.x = f2bf_rne(v.x) | (f2bf_rne(v.y) << 16);
    p.y = f2bf_rne(v.z) | (f2bf_rne(v.w) << 16);
    *(uint2*)(Abr + it * 128 + lane * 2) = p;
  }
  sum = warp_sum64(sum);
  if (lane == 0) {
    const float diag = Ar[n];
    const float ad = (fabsf(diag) < 1e-7f) ? 1.f : 0.f;
    dm[row] = 1.f / sqrtf(sum + ad);
    addf[row] = ad;
  }
}

// hst1[b][f][n] = bf16( dm_row * sum_c x[row][c] * W1[c][f] ), row = b*N+n
__global__ __launch_bounds__(256) void xw_kernel(const float* __restrict__ x,
                                                 const float* __restrict__ W1,
                                                 const float* __restrict__ dm,
                                                 unsigned short* __restrict__ hst) {
  __shared__ float xs[8][FF + 1];
  __shared__ float wl[FF * HH];
  const int tid = threadIdx.x;
  const size_t row0 = (size_t)blockIdx.x * 8;
  for (int k = tid; k < FF * HH; k += 256) wl[k] = W1[k];
  for (int k = tid; k < 8 * FF; k += 256) xs[k >> 6][k & 63] = x[row0 * FF + k];
  __syncthreads();
  const int r = tid >> 5, c = tid & 31;
  float acc = 0.f;
#pragma unroll
  for (int k = 0; k < FF; ++k) acc = fmaf(xs[r][k], wl[k * HH + c], acc);
  const size_t row = row0 + r;
  const int b = (int)(row >> 11);
  const int n = (int)(row & (NN - 1));
  hst[((size_t)b * HH + c) * NN + n] = (unsigned short)f2bf_rne(dm[row] * acc);
}

// One fused GCN layer via MFMA — single-wave blocks, wave-private staging.
// Block = 1 wave = 16-row M-tile x N=32, full K=2048 in 16 chunks of 128.
// Per chunk the wave DMA-stages its own A (16x128) + B (32x128) bf16 into
// its private LDS (triple-buffered) and waits with fine-grained
// s_waitcnt vmcnt(24/12/0) — NO barriers in the K-loop. XOR-granule
// swizzle (granule g of row r at slot g^(r&15)) keeps ds_read_b128
// fragment reads ~conflict-free while the DMA lane map stays contiguous.
// Epilogue consumes acc (C layout: row=q*4+reg, col=lane&15) in-wave.
__global__ __launch_bounds__(64) void layer_kernel(const unsigned short* __restrict__ Abf,
                                                   const unsigned short* __restrict__ hst_in,
                                                   const float* __restrict__ dm,
                                                   const float* __restrict__ addf,
                                                   const float* __restrict__ bias,
                                                   const float* __restrict__ Wn,
                                                   unsigned short* __restrict__ hst_next,
                                                   unsigned int* __restrict__ gmax,
                                                   const int do_pool) {
  __shared__ __align__(16) unsigned char smem[3][12288];  // A 4KB + B 8KB per buf

  const int tid = threadIdx.x;      // 0..63 (one wave)
  const int mb = blockIdx.x & 127;  // 128 M-tiles of 16 rows
  const int b = blockIdx.x >> 7;
  const int mrow0 = mb * 16;
  const int q = tid >> 4;           // 0..3
  const int l15 = tid & 15;

  // --- DMA source pointers (advance by CK per issued chunk) ---
  // Issue i writes LDS bytes [i*1024, i*1024+1024): row r=i*4+q, slot gd=l15,
  // which must hold global granule gl = gd ^ (r&15).
  const unsigned short* aSrc[4];
  const unsigned short* bSrc[8];
#pragma unroll
  for (int i = 0; i < 4; ++i) {
    const int r = i * 4 + q;                  // 0..15
    const int gl = l15 ^ r;
    aSrc[i] = Abf + ((size_t)(b * NN + mrow0 + r)) * NN + gl * 8;
  }
#pragma unroll
  for (int i = 0; i < 8; ++i) {
    const int r = i * 4 + q;                  // 0..31
    const int gl = l15 ^ (r & 15);
    bSrc[i] = hst_in + ((size_t)(b * HH + r)) * NN + gl * 8;
  }

#define ISSUE(buf)                                                        \
  do {                                                                    \
    _Pragma("unroll") for (int i = 0; i < 4; ++i) {                       \
      GLOAD_LDS16(aSrc[i], &smem[buf][i * 1024]);                         \
      aSrc[i] += CK;                                                      \
    }                                                                     \
    _Pragma("unroll") for (int i = 0; i < 8; ++i) {                       \
      GLOAD_LDS16(bSrc[i], &smem[buf][4096 + i * 1024]);                  \
      bSrc[i] += CK;                                                      \
    }                                                                     \
  } while (0)

  floatx4 acc0 = {0.f, 0.f, 0.f, 0.f};  // cols l15
  floatx4 acc1 = {0.f, 0.f, 0.f, 0.f};  // cols 16+l15

  ISSUE(0);
  ISSUE(1);
#pragma unroll
  for (int c = 0; c < NCHK; ++c) {
    if (c + 2 < NCHK) ISSUE((c + 2) % 3);
    if (c <= NCHK - 3) {
      asm volatile("s_waitcnt vmcnt(24)" ::: "memory");  // chunks c+1,c+2 in flight
    } else if (c == NCHK - 2) {
      asm volatile("s_waitcnt vmcnt(12)" ::: "memory");  // chunk c+1 in flight
    } else {
      asm volatile("s_waitcnt vmcnt(0)" ::: "memory");
    }
    const unsigned char* Ab = smem[c % 3];
    const unsigned char* Bb = smem[c % 3] + 4096;
#pragma unroll
    for (int ks = 0; ks < 4; ++ks) {
      const int go = (((ks * 4 + q) ^ l15) * 16);
      short8 af = *(const short8*)(Ab + l15 * 256 + go);
      short8 b0 = *(const short8*)(Bb + l15 * 256 + go);
      short8 b1 = *(const short8*)(Bb + 4096 + l15 * 256 + go);
      acc0 = __builtin_amdgcn_mfma_f32_16x16x32_bf16(af, b0, acc0, 0, 0, 0);
      acc1 = __builtin_amdgcn_mfma_f32_16x16x32_bf16(af, b1, acc1, 0, 0, 0);
    }
  }
#undef ISSUE

  // --- epilogue: h = relu(dm*(acc + add*hsin) + bias) ---
  float h0[4], h1[4];
#pragma unroll
  for (int r = 0; r < 4; ++r) {
    const int row = q * 4 + r;
    const int rg = b * NN + mrow0 + row;
    const float dmv = dm[rg], adv = addf[rg];
    const float hs0 = bf2f(hst_in[((size_t)b * HH + l15) * NN + mrow0 + row]);
    const float hs1 = bf2f(hst_in[((size_t)b * HH + 16 + l15) * NN + mrow0 + row]);
    h0[r] = fmaxf(fmaf(dmv, acc0[r] + adv * hs0, bias[l15]), 0.f);
    h1[r] = fmaxf(fmaf(dmv, acc1[r] + adv * hs1, bias[16 + l15]), 0.f);
  }

  if (do_pool) {
    float m0 = fmaxf(fmaxf(h0[0], h0[1]), fmaxf(h0[2], h0[3]));
    float m1 = fmaxf(fmaxf(h1[0], h1[1]), fmaxf(h1[2], h1[3]));
    m0 = fmaxf(m0, __shfl_xor(m0, 16, 64));
    m0 = fmaxf(m0, __shfl_xor(m0, 32, 64));
    m1 = fmaxf(m1, __shfl_xor(m1, 16, 64));
    m1 = fmaxf(m1, __shfl_xor(m1, 32, 64));
    if (q == 0) {
      atomicMax(&gmax[b * HH + l15], __float_as_uint(m0));
      atomicMax(&gmax[b * HH + 16 + l15], __float_as_uint(m1));
    }
  } else {
    // transpose h through LDS (overlays staging buf 0 — K-loop done, drained)
    float* hb = (float*)&smem[0][0];  // [16][33]
    __syncthreads();  // single wave: cheap; orders overlay reuse
#pragma unroll
    for (int r = 0; r < 4; ++r) {
      const int row = q * 4 + r;
      hb[row * 33 + l15] = h0[r];
      hb[row * 33 + 16 + l15] = h1[r];
    }
    __syncthreads();
    unsigned short o0[4], o1[4];
#pragma unroll
    for (int r = 0; r < 4; ++r) {
      const int row = q * 4 + r;
      const int rg = b * NN + mrow0 + row;
      float s0 = 0.f, s1 = 0.f;
#pragma unroll
      for (int k = 0; k < HH; ++k) {
        const float hv = hb[row * 33 + k];
        s0 = fmaf(hv, Wn[k * HH + l15], s0);
        s1 = fmaf(hv, Wn[k * HH + 16 + l15], s1);
      }
      const float dmv = dm[rg];
      o0[r] = (unsigned short)f2bf_rne(dmv * s0);
      o1[r] = (unsigned short)f2bf_rne(dmv * s1);
    }
    // store: wait — o0[r] holds row q*4+r for col l15; rows q*4..q*4+3 are
    // consecutive in hst_next's n-dim -> one ushort4 per col.
    *(ushort4*)(hst_next + ((size_t)b * HH + l15) * NN + mrow0 + q * 4) =
        *(ushort4*)o0;
    *(ushort4*)(hst_next + ((size_t)b * HH + 16 + l15) * NN + mrow0 + q * 4) =
        *(ushort4*)o1;
  }
}

// out[b] = (relu(g @ Wf1 + bf1)) @ Wf2 + bf2 ; one wave per batch
__global__ __launch_bounds__(64) void head_kernel(const unsigned int* __restrict__ gmax,
                                                  const float* __restrict__ Wf1,
                                                  const float* __restrict__ bf1,
                                                  const float* __restrict__ Wf2,
                                                  const float* __restrict__ bf2,
                                                  float* __restrict__ out) {
  const int b = blockIdx.x;
  const int t = threadIdx.x;  // 0..63 hidden units
  float acc = bf1[t];
#pragma unroll
  for (int c = 0; c < HH; ++c)
    acc = fmaf(__uint_as_float(gmax[b * HH + c]), Wf1[c * (2 * HH) + t], acc);
  acc = fmaxf(acc, 0.f);
  float v = acc * Wf2[t];
  v = warp_sum64(v);
  if (t == 0) out[b] = v + bf2[0];
}

extern "C" void kernel_launch(void* const* d_in, const int* in_sizes, int n_in,
                              void* d_out, int out_size, void* d_ws, size_t ws_size,
                              hipStream_t stream) {
  const float* x   = (const float*)d_in[0];
  const float* a   = (const float*)d_in[1];
  const float* W1  = (const float*)d_in[2];
  const float* b1  = (const float*)d_in[3];
  const float* W2  = (const float*)d_in[4];
  const float* b2  = (const float*)d_in[5];
  const float* W3  = (const float*)d_in[6];
  const float* b3  = (const float*)d_in[7];
  const float* Wf1 = (const float*)d_in[8];
  const float* bf1 = (const float*)d_in[9];
  const float* Wf2 = (const float*)d_in[10];
  const float* bf2 = (const float*)d_in[11];
  float* out = (float*)d_out;

  float* ws = (float*)d_ws;
  const size_t BN = (size_t)BB * NN;  // 16384
  float* dm   = ws;                                       // 16384 f
  float* addf = dm + BN;                                  // 16384 f
  unsigned int* gmax = (unsigned int*)(addf + BN);        // 256 u32
  unsigned short* hst_a = (unsigned short*)(gmax + 256);  // 1 MB
  unsigned short* hst_b = hst_a + BN * HH;                // 1 MB
  unsigned short* Abf = hst_b + BN * HH;                  // 67 MB bf16 A
  // total ws use ~69.5 MB

  hipMemsetAsync(gmax, 0, BB * HH * sizeof(unsigned int), stream);

  deg_cvt_kernel<<<BN / 4, 256, 0, stream>>>(a, dm, addf, Abf);
  xw_kernel<<<BN / 8, 256, 0, stream>>>(x, W1, dm, hst_a);

  layer_kernel<<<BB * 128, 64, 0, stream>>>(Abf, hst_a, dm, addf, b1, W2, hst_b, nullptr, 0);
  layer_kernel<<<BB * 128, 64, 0, stream>>>(Abf, hst_b, dm, addf, b2, W3, hst_a, nullptr, 0);
  layer_kernel<<<BB * 128, 64, 0, stream>>>(Abf, hst_a, dm, addf, b3, nullptr, nullptr, gmax, 1);

  head_kernel<<<BB, 64, 0, stream>>>(gmax, Wf1, bf1, Wf2, bf2, out);
}